// Round 1
// 1473.018 us; speedup vs baseline: 1.1743x; 1.1743x over previous
//
#include <hip/hip_runtime.h>
#include <stdint.h>

// Problem constants
#define B_   16
#define N_   4096
#define C_   1152
#define H_   16
#define HD_  72
#define S_   64
#define M_   (B_*N_)      // 65536 rows
#define KV_  144          // 2*HD

using f16   = _Float16;
using f16x8 = __attribute__((ext_vector_type(8))) _Float16;
using f16x4 = __attribute__((ext_vector_type(4))) _Float16;
using f32x4 = __attribute__((ext_vector_type(4))) float;

#define GLD16(g, l) __builtin_amdgcn_global_load_lds( \
    (const __attribute__((address_space(1))) uint32_t*)(g), \
    (__attribute__((address_space(3))) uint32_t*)(l), 16, 0, 0)

// ---------------------------------------------------------------------------
// x fp32 -> fp16, 8 elements/thread, exact grid.
// ---------------------------------------------------------------------------
__global__ __launch_bounds__(256) void convx_k(
    const float* __restrict__ src, f16* __restrict__ dst) {
  long i = ((long)blockIdx.x * 256 + threadIdx.x) * 8;
  float4 a = *(const float4*)(src + i);
  float4 b = *(const float4*)(src + i + 4);
  f16x8 o = {(f16)a.x, (f16)a.y, (f16)a.z, (f16)a.w,
             (f16)b.x, (f16)b.y, (f16)b.z, (f16)b.w};
  *(f16x8*)(dst + i) = o;
}

// ---------------------------------------------------------------------------
// Transpose+convert W[K,N] fp32 -> Wt[N,K] fp16.  K mult of 32; N arbitrary.
// ---------------------------------------------------------------------------
__global__ __launch_bounds__(256) void transc_k(
    const float* __restrict__ src, f16* __restrict__ dst, int K, int N) {
  __shared__ f16 tile[32][33];
  int k0 = blockIdx.x * 32, n0 = blockIdx.y * 32;
  int tx = threadIdx.x & 31, ty = threadIdx.x >> 5;   // 32 x 8
#pragma unroll
  for (int i = 0; i < 4; i++) {
    int k = k0 + ty + i * 8, n = n0 + tx;
    if (n < N) tile[ty + i * 8][tx] = (f16)src[(long)k * N + n];
  }
  __syncthreads();
#pragma unroll
  for (int i = 0; i < 4; i++) {
    int n = n0 + ty + i * 8, k = k0 + tx;
    if (n < N) dst[(long)n * K + k] = tile[tx][ty + i * 8];
  }
}

// ---------------------------------------------------------------------------
// GEMM: C[M,N] = A[M,K] @ Bt[N,K]^T + bias.  fp16 in, fp32 accum (MFMA),
// OutT out.  128x128 tile, BK=32, 4 waves each doing a 64x64 quadrant.
// ---------------------------------------------------------------------------
#define BM 128
#define BN 128
#define BK 32
template <typename OutT>
__global__ __launch_bounds__(256) void gemm_bt(
    const f16* __restrict__ A, const f16* __restrict__ Bt,
    const float* __restrict__ bias, OutT* __restrict__ Cc,
    int M, int N, int K, int nbn) {
  __shared__ f16 As[BM][BK];
  __shared__ f16 Bs[BN][BK];
  int bid = blockIdx.x;
  int bm = bid / nbn, bn = bid % nbn;
  int m0 = bm * BM, n0 = bn * BN;
  int t = threadIdx.x;
  int w = t >> 6, lane = t & 63;
  int wr = w >> 1, wc = w & 1;
  int m16 = lane & 15, q4 = lane >> 4;

  f32x4 acc[4][4];
#pragma unroll
  for (int i = 0; i < 4; i++)
#pragma unroll
    for (int j = 0; j < 4; j++) acc[i][j] = (f32x4){0.f, 0.f, 0.f, 0.f};

  int srow = t >> 2;
  int scol = (t & 3) * 8;
  const f16* Ar0 = A + (long)(m0 + srow) * K + scol;
  const f16* Ar1 = A + (long)(m0 + 64 + srow) * K + scol;
  int br0 = n0 + srow;      if (br0 >= N) br0 = N - 1;
  int br1 = n0 + 64 + srow; if (br1 >= N) br1 = N - 1;
  const f16* Br0 = Bt + (long)br0 * K + scol;
  const f16* Br1 = Bt + (long)br1 * K + scol;
  char* AsL = (char*)&As[0][0] + w * 1024;   // wave-uniform LDS base
  char* BsL = (char*)&Bs[0][0] + w * 1024;

  for (int kk = 0; kk < K; kk += BK) {
    __syncthreads();
    GLD16(Ar0 + kk, AsL);
    GLD16(Ar1 + kk, AsL + 4096);
    GLD16(Br0 + kk, BsL);
    GLD16(Br1 + kk, BsL + 4096);
    __syncthreads();

    f16x8 af[4], bf[4];
#pragma unroll
    for (int i = 0; i < 4; i++)
      af[i] = *(const f16x8*)&As[wr * 64 + i * 16 + m16][q4 * 8];
#pragma unroll
    for (int j = 0; j < 4; j++)
      bf[j] = *(const f16x8*)&Bs[wc * 64 + j * 16 + m16][q4 * 8];
#pragma unroll
    for (int i = 0; i < 4; i++)
#pragma unroll
      for (int j = 0; j < 4; j++)
        acc[i][j] = __builtin_amdgcn_mfma_f32_16x16x32_f16(af[i], bf[j], acc[i][j], 0, 0, 0);
  }

  // D layout: col = lane&15, row = (lane>>4)*4 + r
#pragma unroll
  for (int j = 0; j < 4; j++) {
    int col = n0 + wc * 64 + j * 16 + m16;
    if (col < N) {
      float bv = bias[col];
#pragma unroll
      for (int i = 0; i < 4; i++) {
        int rb = m0 + wr * 64 + i * 16 + q4 * 4;
#pragma unroll
        for (int r = 0; r < 4; r++)
          Cc[(long)(rb + r) * N + col] = (OutT)(acc[i][j][r] + bv);
      }
    }
  }
}

// ---------------------------------------------------------------------------
// Per-(b,h) focused-norm sums: sum relu(q)^2, relu(q)^6.  q [M,C] fp16.
// ---------------------------------------------------------------------------
__global__ __launch_bounds__(384) void qsums_k(
    const f16* __restrict__ q, float* __restrict__ s2o, float* __restrict__ s6o) {
  int b = blockIdx.y, chunk = blockIdx.x, t = threadIdx.x;
  float s2[3] = {0.f, 0.f, 0.f}, s6[3] = {0.f, 0.f, 0.f};
  const f16* base = q + (long)(b * N_ + chunk * 128) * C_;
  for (int n = 0; n < 128; n++) {
#pragma unroll
    for (int s = 0; s < 3; s++) {
      float v = fmaxf((float)base[(long)n * C_ + t + s * 384], 0.f);
      float v2 = v * v, v3 = v2 * v;
      s2[s] += v2; s6[s] += v3 * v3;
    }
  }
  __shared__ float l2[H_], l6[H_];
  if (t < H_) { l2[t] = 0.f; l6[t] = 0.f; }
  __syncthreads();
#pragma unroll
  for (int s = 0; s < 3; s++) {
    int h = (t + s * 384) / HD_;
    atomicAdd(&l2[h], s2[s]); atomicAdd(&l6[h], s6[s]);
  }
  __syncthreads();
  if (t < H_) { atomicAdd(&s2o[b * H_ + t], l2[t]); atomicAdd(&s6o[b * H_ + t], l6[t]); }
}

// Per-b sums for k = kv_lin[..., 0:72]
__global__ __launch_bounds__(256) void ksums_k(
    const f16* __restrict__ kv, float* __restrict__ s2o, float* __restrict__ s6o) {
  int b = blockIdx.y, chunk = blockIdx.x, t = threadIdx.x;
  float s2 = 0.f, s6 = 0.f;
  const f16* base = kv + (long)(b * N_ + chunk * 128) * KV_;
  for (int idx = t; idx < 128 * HD_; idx += 256) {
    int n = idx / HD_, d = idx % HD_;
    float v = fmaxf((float)base[(long)n * KV_ + d], 0.f);
    float v2 = v * v, v3 = v2 * v;
    s2 += v2; s6 += v3 * v3;
  }
  __shared__ float l[2];
  if (t < 2) l[t] = 0.f;
  __syncthreads();
  atomicAdd(&l[0], s2); atomicAdd(&l[1], s6);
  __syncthreads();
  if (t == 0) atomicAdd(&s2o[b], l[0]);
  if (t == 1) atomicAdd(&s6o[b], l[1]);
}

// ---------------------------------------------------------------------------
// kv_acc[b,d,e] += sum_n relu(k)^3[b,n,d] * v[b,n,e]   (unscaled; fp32 atomics)
// ---------------------------------------------------------------------------
__global__ __launch_bounds__(256) void kvacc_k(
    const f16* __restrict__ kv, float* __restrict__ kvac) {
  int b = blockIdx.y, chunk = blockIdx.x, t = threadIdx.x;
  __shared__ f16 kt[64 * KV_];          // 18,432 B
  __shared__ float k3[64 * HD_];        // 18,432 B
  const f16* src = kv + (long)(b * N_ + chunk * 64) * KV_;
  for (int i = t; i < (64 * KV_) / 8; i += 256)
    ((int4*)kt)[i] = ((const int4*)src)[i];
  __syncthreads();
  for (int i = t; i < 64 * HD_; i += 256) {
    int n = i / HD_, d = i % HD_;
    float v = fmaxf((float)kt[n * KV_ + d], 0.f);
    k3[i] = v * v * v;
  }
  __syncthreads();
  for (int og = t; og < HD_ * (HD_ / 4); og += 256) {   // 72 * 18 = 1296
    int d = og / 18, e0 = (og % 18) * 4;
    float a0 = 0.f, a1 = 0.f, a2 = 0.f, a3 = 0.f;
    for (int n = 0; n < 64; n++) {
      float kq = k3[n * HD_ + d];
      f16x4 vv = *(const f16x4*)&kt[n * KV_ + HD_ + e0];
      a0 += kq * (float)vv.x; a1 += kq * (float)vv.y;
      a2 += kq * (float)vv.z; a3 += kq * (float)vv.w;
    }
    float* dst = kvac + ((long)b * HD_ + d) * HD_ + e0;
    atomicAdd(dst + 0, a0); atomicAdd(dst + 1, a1);
    atomicAdd(dst + 2, a2); atomicAdd(dst + 3, a3);
  }
}

// ---------------------------------------------------------------------------
// prep_k: build zero-padded transposed kvT[b][80][104] f16 (kvT[b][e][k] =
// kvac[b][k][e], pad rows/cols = 0) and scale sc[b][h].
// ---------------------------------------------------------------------------
#define KT_E 80
#define KT_K 104
__global__ __launch_bounds__(256) void prep_k(
    const float* __restrict__ kvac,
    const float* __restrict__ sq2, const float* __restrict__ sq6,
    const float* __restrict__ sk2, const float* __restrict__ sk6,
    f16* __restrict__ kvT, float* __restrict__ sc) {
  int b = blockIdx.x, t = threadIdx.x;
  for (int i = t; i < KT_E * KT_K; i += 256) {
    int e = i / KT_K, k = i % KT_K;
    f16 v = (f16)0.f;
    if (e < HD_ && k < HD_) v = (f16)kvac[((long)b * HD_ + k) * HD_ + e];
    kvT[(long)b * KT_E * KT_K + i] = v;
  }
  if (t < H_) {
    float s6q = sq6[b * H_ + t], s6k = sk6[b];
    float rq = (s6q > 0.f) ? sqrtf(sq2[b * H_ + t]) / sqrtf(s6q) : 0.f;
    float rk = (s6k > 0.f) ? sqrtf(sk2[b]) / sqrtf(s6k) : 0.f;
    sc[b * H_ + t] = rq * rk;
  }
}

// ---------------------------------------------------------------------------
// dwc_k: depthwise 3x3 conv on v -> dwcbuf[b][n][72] f16.
// ---------------------------------------------------------------------------
__global__ __launch_bounds__(256) void dwc_k(
    const f16* __restrict__ kv, const float* __restrict__ dwc_w,
    const float* __restrict__ dwc_b, f16* __restrict__ out) {
  int b = blockIdx.y, n0 = blockIdx.x * 32, t = threadIdx.x;
  for (int idx = t; idx < 32 * HD_; idx += 256) {
    int nl = idx / HD_, e = idx % HD_;
    int n = n0 + nl, i = n >> 6, j = n & 63;
    float s = dwc_b[e];
#pragma unroll
    for (int di = 0; di < 3; di++) {
      int ii = i + di - 1;
      if (ii < 0 || ii >= S_) continue;
#pragma unroll
      for (int dj = 0; dj < 3; dj++) {
        int jj = j + dj - 1;
        if (jj < 0 || jj >= S_) continue;
        s += dwc_w[e * 9 + di * 3 + dj] *
             (float)kv[(long)(b * N_ + ii * S_ + jj) * KV_ + HD_ + e];
      }
    }
    out[((long)b * N_ + n) * HD_ + e] = (f16)s;
  }
}

// ---------------------------------------------------------------------------
// attn_k: per (b,h,128-row block):  y = sc[b,h] * relu(q)^3 @ kvl + dwc,
// written in place over q (disjoint column slice per h).  MFMA 16x16x32 f16,
// K padded 72->96, N padded 72->80.  LDS: qs[128][104] (reused for y staging),
// kvs[80][104].  43.3 KB -> 3 blocks/CU.
// ---------------------------------------------------------------------------
#define AT_M 128
__global__ __launch_bounds__(256) void attn_k(
    f16* __restrict__ q,                 // read q, write y in place
    const f16* __restrict__ kvT,         // [B][80][104]
    const float* __restrict__ sc,        // [B][H]
    const f16* __restrict__ dwcb) {      // [B][N][72]
  int nb = blockIdx.x, h = blockIdx.y, b = blockIdx.z;
  int n0 = nb * AT_M;
  int t = threadIdx.x;
  __shared__ f16 qs[AT_M][KT_K];     // 26,624 B  (relu^3 q, then y staging)
  __shared__ f16 kvs[KT_E][KT_K];    // 16,640 B

  // stage kvT (already padded/transposed) -- 1040 x 16B
  const f16* kvsrc = kvT + (long)b * KT_E * KT_K;
  for (int i = t; i < KT_E * KT_K / 8; i += 256)
    *(f16x8*)((f16*)kvs + (long)i * 8) = *(const f16x8*)(kvsrc + (long)i * 8);

  // stage q -> relu^3 (f16) ; 128 rows x 9 chunks of 8
  const f16* qbase = q + ((long)(b * N_ + n0)) * C_ + h * HD_;
  for (int i = t; i < AT_M * 9; i += 256) {
    int r = i / 9, ch = i % 9;
    f16x8 v = *(const f16x8*)(qbase + (long)r * C_ + ch * 8);
    f16x8 o;
#pragma unroll
    for (int u = 0; u < 8; u++) {
      float f = fmaxf((float)v[u], 0.f);
      o[u] = (f16)(f * f * f);
    }
    *(f16x8*)&qs[r][ch * 8] = o;
  }
  // zero K-pad cols 72..95 (cols 96..103 never read)
  f16x8 z = {(f16)0.f, (f16)0.f, (f16)0.f, (f16)0.f,
             (f16)0.f, (f16)0.f, (f16)0.f, (f16)0.f};
  for (int i = t; i < AT_M * 3; i += 256) {
    int r = i / 3, ch = i % 3;
    *(f16x8*)&qs[r][72 + ch * 8] = z;
  }
  __syncthreads();

  // MFMA: wave w owns rows w*32..w*32+31 (2 m-tiles), 5 n-tiles, 3 K-steps
  int w = t >> 6, lane = t & 63;
  int m16 = lane & 15, q4 = lane >> 4;
  f32x4 acc[2][5];
#pragma unroll
  for (int i = 0; i < 2; i++)
#pragma unroll
    for (int j = 0; j < 5; j++) acc[i][j] = (f32x4){0.f, 0.f, 0.f, 0.f};

#pragma unroll
  for (int k = 0; k < 96; k += 32) {
    f16x8 af[2], bf[5];
#pragma unroll
    for (int i = 0; i < 2; i++)
      af[i] = *(const f16x8*)&qs[w * 32 + i * 16 + m16][k + q4 * 8];
#pragma unroll
    for (int j = 0; j < 5; j++)
      bf[j] = *(const f16x8*)&kvs[j * 16 + m16][k + q4 * 8];
#pragma unroll
    for (int i = 0; i < 2; i++)
#pragma unroll
      for (int j = 0; j < 5; j++)
        acc[i][j] = __builtin_amdgcn_mfma_f32_16x16x32_f16(af[i], bf[j], acc[i][j], 0, 0, 0);
  }

  float s = sc[b * H_ + h];
  __syncthreads();   // all waves done reading qs -> reuse as y staging

  // D layout: col = lane&15, row = (lane>>4)*4 + r.  Mask cols >= 72 (j==4).
#pragma unroll
  for (int j = 0; j < 5; j++) {
    if (j == 4 && m16 >= 8) continue;
#pragma unroll
    for (int i = 0; i < 2; i++) {
#pragma unroll
      for (int r = 0; r < 4; r++)
        qs[w * 32 + i * 16 + q4 * 4 + r][j * 16 + m16] = (f16)(acc[i][j][r] * s);
    }
  }
  __syncthreads();

  // coalesced write: y = ys + dwc
  const f16* db = dwcb + ((long)(b * N_ + n0)) * HD_;
  f16* yb = q + ((long)(b * N_ + n0)) * C_ + h * HD_;
  for (int i = t; i < AT_M * 9; i += 256) {
    int r = i / 9, ch = i % 9;
    f16x8 a = *(const f16x8*)&qs[r][ch * 8];
    f16x8 d = *(const f16x8*)(db + (long)r * HD_ + ch * 8);
    f16x8 o;
#pragma unroll
    for (int u = 0; u < 8; u++)
      o[u] = (f16)((float)a[u] + (float)d[u]);
    *(f16x8*)(yb + (long)r * C_ + ch * 8) = o;
  }
}

// ---------------------------------------------------------------------------
extern "C" void kernel_launch(void* const* d_in, const int* in_sizes, int n_in,
                              void* d_out, int out_size, void* d_ws, size_t ws_size,
                              hipStream_t stream) {
  const float* x      = (const float*)d_in[0];
  const float* wq_w   = (const float*)d_in[1];
  const float* wq_b   = (const float*)d_in[2];
  const float* wkv_w  = (const float*)d_in[3];
  const float* wkv_b  = (const float*)d_in[4];
  const float* dwc_w  = (const float*)d_in[5];
  const float* dwc_b  = (const float*)d_in[6];
  const float* proj_w = (const float*)d_in[7];
  const float* proj_b = (const float*)d_in[8];
  float* out = (float*)d_out;
  char* ws = (char*)d_ws;

  // x_h (fp16 copy of x) lives in d_out's first half — dead before final GEMM.
  f16* x_h = (f16*)d_out;
  // Upper half of d_out: dwcbuf / kvT / sc — all consumed by attn_k,
  // which runs before the final GEMM overwrites d_out.
  char* dtop = (char*)d_out + (size_t)M_ * C_ * 2;        // +150,994,944
  f16* dwcb = (f16*)dtop;                                  // 9,437,184 B
  f16* kvT  = (f16*)(dtop + (size_t)B_ * N_ * HD_ * 2);    //   266,240 B
  float* sc = (float*)(dtop + (size_t)B_ * N_ * HD_ * 2
                            + (size_t)B_ * KT_E * KT_K * 2);

  size_t off = 0;
  f16* wq_t   = (f16*)(ws + off); off += (size_t)C_ * C_ * 2;     // 2,654,208
  f16* proj_t = (f16*)(ws + off); off += (size_t)C_ * C_ * 2;
  f16* wkv_t  = (f16*)(ws + off); off += (size_t)KV_ * C_ * 2;    // 331,776
  f16* q_lin  = (f16*)(ws + off); off += (size_t)M_ * C_ * 2;     // 150,994,944
  f16* kv_lin = (f16*)(ws + off); off += (size_t)M_ * KV_ * 2;    // 18,874,368
  char* zbase = ws + off;
  float* sq2  = (float*)(ws + off); off += 1024;
  float* sq6  = (float*)(ws + off); off += 1024;
  float* sk2  = (float*)(ws + off); off += 1024;
  float* sk6  = (float*)(ws + off); off += 1024;
  float* kvac = (float*)(ws + off); off += (size_t)B_ * HD_ * HD_ * 4;
  size_t zlen = (size_t)(ws + off - zbase);

  hipMemsetAsync(zbase, 0, zlen, stream);

  convx_k<<<dim3((M_ * C_) / (256 * 8)), 256, 0, stream>>>(x, x_h);
  transc_k<<<dim3(C_ / 32, C_ / 32), 256, 0, stream>>>(wq_w, wq_t, C_, C_);
  transc_k<<<dim3(C_ / 32, (KV_ + 31) / 32), 256, 0, stream>>>(wkv_w, wkv_t, C_, KV_);
  transc_k<<<dim3(C_ / 32, C_ / 32), 256, 0, stream>>>(proj_w, proj_t, C_, C_);

  // q_lin = x @ wq + b   (M=65536, N=1152, K=1152)
  gemm_bt<f16><<<dim3((M_ / BM) * (C_ / BN)), 256, 0, stream>>>(
      x_h, wq_t, wq_b, q_lin, M_, C_, C_, C_ / BN);
  // kv_lin = x @ wkv + b (N=144 -> 2 col-blocks with tail clamp)
  gemm_bt<f16><<<dim3((M_ / BM) * 2), 256, 0, stream>>>(
      x_h, wkv_t, wkv_b, kv_lin, M_, KV_, C_, 2);

  qsums_k<<<dim3(32, B_), 384, 0, stream>>>(q_lin, sq2, sq6);
  ksums_k<<<dim3(32, B_), 256, 0, stream>>>(kv_lin, sk2, sk6);
  kvacc_k<<<dim3(64, B_), 256, 0, stream>>>(kv_lin, kvac);

  prep_k<<<dim3(B_), 256, 0, stream>>>(kvac, sq2, sq6, sk2, sk6, kvT, sc);
  dwc_k<<<dim3(N_ / 32, B_), 256, 0, stream>>>(kv_lin, dwc_w, dwc_b, dwcb);

  attn_k<<<dim3(N_ / AT_M, H_, B_), 256, 0, stream>>>(q_lin, kvT, sc, dwcb);

  // out = y @ proj + b  (fp32 store to d_out)
  gemm_bt<float><<<dim3((M_ / BM) * (C_ / BN)), 256, 0, stream>>>(
      q_lin, proj_t, proj_b, out, M_, C_, C_, C_ / BN);
}

// Round 2
// 1381.211 us; speedup vs baseline: 1.2523x; 1.0665x over previous
//
#include <hip/hip_runtime.h>
#include <stdint.h>

// Problem constants
#define B_   16
#define N_   4096
#define C_   1152
#define H_   16
#define HD_  72
#define S_   64
#define M_   (B_*N_)      // 65536 rows
#define KV_  144          // 2*HD
#define QKVC_ (C_ + KV_)  // 1296 fused row width

using f16   = _Float16;
using f16x8 = __attribute__((ext_vector_type(8))) _Float16;
using f16x4 = __attribute__((ext_vector_type(4))) _Float16;
using f32x4 = __attribute__((ext_vector_type(4))) float;

#define GLD16(g, l) __builtin_amdgcn_global_load_lds( \
    (const __attribute__((address_space(1))) uint32_t*)(g), \
    (__attribute__((address_space(3))) uint32_t*)(l), 16, 0, 0)

// ---------------------------------------------------------------------------
// x fp32 -> fp16, 8 elements/thread, exact grid.
// ---------------------------------------------------------------------------
__global__ __launch_bounds__(256) void convx_k(
    const float* __restrict__ src, f16* __restrict__ dst) {
  long i = ((long)blockIdx.x * 256 + threadIdx.x) * 8;
  float4 a = *(const float4*)(src + i);
  float4 b = *(const float4*)(src + i + 4);
  f16x8 o = {(f16)a.x, (f16)a.y, (f16)a.z, (f16)a.w,
             (f16)b.x, (f16)b.y, (f16)b.z, (f16)b.w};
  *(f16x8*)(dst + i) = o;
}

// ---------------------------------------------------------------------------
// Transpose+convert W[K,N] fp32 -> Wt[N,K] fp16.  K mult of 32; N arbitrary.
// ---------------------------------------------------------------------------
__global__ __launch_bounds__(256) void transc_k(
    const float* __restrict__ src, f16* __restrict__ dst, int K, int N) {
  __shared__ f16 tile[32][33];
  int k0 = blockIdx.x * 32, n0 = blockIdx.y * 32;
  int tx = threadIdx.x & 31, ty = threadIdx.x >> 5;   // 32 x 8
#pragma unroll
  for (int i = 0; i < 4; i++) {
    int k = k0 + ty + i * 8, n = n0 + tx;
    if (n < N) tile[ty + i * 8][tx] = (f16)src[(long)k * N + n];
  }
  __syncthreads();
#pragma unroll
  for (int i = 0; i < 4; i++) {
    int n = n0 + ty + i * 8, k = k0 + tx;
    if (n < N) dst[(long)n * K + k] = tile[tx][ty + i * 8];
  }
}

// ---------------------------------------------------------------------------
// GEMM: C[M,N] = A[M,K] @ Bt[N,K]^T + bias.  fp16 in, fp32 accum (MFMA),
// OutT out.  128x128 tile, BK=32, 4 waves each doing a 64x64 quadrant.
// A row stride = lda (>= K).  Bijective XCD swizzle: gridDim.x % 8 == 0.
// ---------------------------------------------------------------------------
#define BM 128
#define BN 128
#define BK 32
template <typename OutT>
__global__ __launch_bounds__(256) void gemm_bt(
    const f16* __restrict__ A, const f16* __restrict__ Bt,
    const float* __restrict__ bias, OutT* __restrict__ Cc,
    int M, int N, int K, int lda, int nbn) {
  __shared__ f16 As[BM][BK];
  __shared__ f16 Bs[BN][BK];
  // XCD-aware swizzle: XCD x owns contiguous bid chunk -> contiguous bm
  // range; the nbn blocks sharing an A-panel stay on one XCD's L2.
  int bid = blockIdx.x;
  int cpx = gridDim.x >> 3;
  bid = (bid & 7) * cpx + (bid >> 3);
  int bm = bid / nbn, bn = bid % nbn;
  int m0 = bm * BM, n0 = bn * BN;
  int t = threadIdx.x;
  int w = t >> 6, lane = t & 63;
  int wr = w >> 1, wc = w & 1;
  int m16 = lane & 15, q4 = lane >> 4;

  f32x4 acc[4][4];
#pragma unroll
  for (int i = 0; i < 4; i++)
#pragma unroll
    for (int j = 0; j < 4; j++) acc[i][j] = (f32x4){0.f, 0.f, 0.f, 0.f};

  int srow = t >> 2;
  int scol = (t & 3) * 8;
  const f16* Ar0 = A + (long)(m0 + srow) * lda + scol;
  const f16* Ar1 = A + (long)(m0 + 64 + srow) * lda + scol;
  int br0 = n0 + srow;      if (br0 >= N) br0 = N - 1;
  int br1 = n0 + 64 + srow; if (br1 >= N) br1 = N - 1;
  const f16* Br0 = Bt + (long)br0 * K + scol;
  const f16* Br1 = Bt + (long)br1 * K + scol;
  char* AsL = (char*)&As[0][0] + w * 1024;   // wave-uniform LDS base
  char* BsL = (char*)&Bs[0][0] + w * 1024;

  for (int kk = 0; kk < K; kk += BK) {
    __syncthreads();
    GLD16(Ar0 + kk, AsL);
    GLD16(Ar1 + kk, AsL + 4096);
    GLD16(Br0 + kk, BsL);
    GLD16(Br1 + kk, BsL + 4096);
    __syncthreads();

    f16x8 af[4], bf[4];
#pragma unroll
    for (int i = 0; i < 4; i++)
      af[i] = *(const f16x8*)&As[wr * 64 + i * 16 + m16][q4 * 8];
#pragma unroll
    for (int j = 0; j < 4; j++)
      bf[j] = *(const f16x8*)&Bs[wc * 64 + j * 16 + m16][q4 * 8];
#pragma unroll
    for (int i = 0; i < 4; i++)
#pragma unroll
      for (int j = 0; j < 4; j++)
        acc[i][j] = __builtin_amdgcn_mfma_f32_16x16x32_f16(af[i], bf[j], acc[i][j], 0, 0, 0);
  }

  // D layout: col = lane&15, row = (lane>>4)*4 + r
#pragma unroll
  for (int j = 0; j < 4; j++) {
    int col = n0 + wc * 64 + j * 16 + m16;
    if (col < N) {
      float bv = bias[col];
#pragma unroll
      for (int i = 0; i < 4; i++) {
        int rb = m0 + wr * 64 + i * 16 + q4 * 4;
#pragma unroll
        for (int r = 0; r < 4; r++)
          Cc[(long)(rb + r) * N + col] = (OutT)(acc[i][j][r] + bv);
      }
    }
  }
}

// ---------------------------------------------------------------------------
// Per-(b,h) focused-norm sums over q part of qkv: sum relu^2, relu^6.
// ---------------------------------------------------------------------------
__global__ __launch_bounds__(384) void qsums_k(
    const f16* __restrict__ q, float* __restrict__ s2o, float* __restrict__ s6o) {
  int b = blockIdx.y, chunk = blockIdx.x, t = threadIdx.x;
  float s2[3] = {0.f, 0.f, 0.f}, s6[3] = {0.f, 0.f, 0.f};
  const f16* base = q + (long)(b * N_ + chunk * 128) * QKVC_;
  for (int n = 0; n < 128; n++) {
#pragma unroll
    for (int s = 0; s < 3; s++) {
      float v = fmaxf((float)base[(long)n * QKVC_ + t + s * 384], 0.f);
      float v2 = v * v, v3 = v2 * v;
      s2[s] += v2; s6[s] += v3 * v3;
    }
  }
  __shared__ float l2[H_], l6[H_];
  if (t < H_) { l2[t] = 0.f; l6[t] = 0.f; }
  __syncthreads();
#pragma unroll
  for (int s = 0; s < 3; s++) {
    int h = (t + s * 384) / HD_;
    atomicAdd(&l2[h], s2[s]); atomicAdd(&l6[h], s6[s]);
  }
  __syncthreads();
  if (t < H_) { atomicAdd(&s2o[b * H_ + t], l2[t]); atomicAdd(&s6o[b * H_ + t], l6[t]); }
}

// Per-b sums for k = qkv[..., C_:C_+72]
__global__ __launch_bounds__(256) void ksums_k(
    const f16* __restrict__ qkv, float* __restrict__ s2o, float* __restrict__ s6o) {
  int b = blockIdx.y, chunk = blockIdx.x, t = threadIdx.x;
  float s2 = 0.f, s6 = 0.f;
  const f16* base = qkv + (long)(b * N_ + chunk * 128) * QKVC_ + C_;
  for (int idx = t; idx < 128 * HD_; idx += 256) {
    int n = idx / HD_, d = idx % HD_;
    float v = fmaxf((float)base[(long)n * QKVC_ + d], 0.f);
    float v2 = v * v, v3 = v2 * v;
    s2 += v2; s6 += v3 * v3;
  }
  __shared__ float l[2];
  if (t < 2) l[t] = 0.f;
  __syncthreads();
  atomicAdd(&l[0], s2); atomicAdd(&l[1], s6);
  __syncthreads();
  if (t == 0) atomicAdd(&s2o[b], l[0]);
  if (t == 1) atomicAdd(&s6o[b], l[1]);
}

// ---------------------------------------------------------------------------
// kv_acc[b,d,e] += sum_n relu(k)^3[b,n,d] * v[b,n,e]   (unscaled; fp32 atomics)
// ---------------------------------------------------------------------------
__global__ __launch_bounds__(256) void kvacc_k(
    const f16* __restrict__ qkv, float* __restrict__ kvac) {
  int b = blockIdx.y, chunk = blockIdx.x, t = threadIdx.x;
  __shared__ f16 kt[64 * KV_];          // 18,432 B
  __shared__ float k3[64 * HD_];        // 18,432 B
  const f16* src = qkv + (long)(b * N_ + chunk * 64) * QKVC_ + C_;
  for (int i = t; i < 64 * (KV_ / 8); i += 256) {   // 64 rows x 18 int4
    int n = i / (KV_ / 8), c = i % (KV_ / 8);
    ((int4*)kt)[i] = *(const int4*)(src + (long)n * QKVC_ + c * 8);
  }
  __syncthreads();
  for (int i = t; i < 64 * HD_; i += 256) {
    int n = i / HD_, d = i % HD_;
    float v = fmaxf((float)kt[n * KV_ + d], 0.f);
    k3[i] = v * v * v;
  }
  __syncthreads();
  for (int og = t; og < HD_ * (HD_ / 4); og += 256) {   // 72 * 18 = 1296
    int d = og / 18, e0 = (og % 18) * 4;
    float a0 = 0.f, a1 = 0.f, a2 = 0.f, a3 = 0.f;
    for (int n = 0; n < 64; n++) {
      float kq = k3[n * HD_ + d];
      f16x4 vv = *(const f16x4*)&kt[n * KV_ + HD_ + e0];
      a0 += kq * (float)vv.x; a1 += kq * (float)vv.y;
      a2 += kq * (float)vv.z; a3 += kq * (float)vv.w;
    }
    float* dst = kvac + ((long)b * HD_ + d) * HD_ + e0;
    atomicAdd(dst + 0, a0); atomicAdd(dst + 1, a1);
    atomicAdd(dst + 2, a2); atomicAdd(dst + 3, a3);
  }
}

// ---------------------------------------------------------------------------
// prep_k: build zero-padded transposed kvT[b][80][104] f16 (kvT[b][e][k] =
// kvac[b][k][e], pad rows/cols = 0) and scale sc[b][h].
// ---------------------------------------------------------------------------
#define KT_E 80
#define KT_K 104
__global__ __launch_bounds__(256) void prep_k(
    const float* __restrict__ kvac,
    const float* __restrict__ sq2, const float* __restrict__ sq6,
    const float* __restrict__ sk2, const float* __restrict__ sk6,
    f16* __restrict__ kvT, float* __restrict__ sc) {
  int b = blockIdx.x, t = threadIdx.x;
  for (int i = t; i < KT_E * KT_K; i += 256) {
    int e = i / KT_K, k = i % KT_K;
    f16 v = (f16)0.f;
    if (e < HD_ && k < HD_) v = (f16)kvac[((long)b * HD_ + k) * HD_ + e];
    kvT[(long)b * KT_E * KT_K + i] = v;
  }
  if (t < H_) {
    float s6q = sq6[b * H_ + t], s6k = sk6[b];
    float rq = (s6q > 0.f) ? sqrtf(sq2[b * H_ + t]) / sqrtf(s6q) : 0.f;
    float rk = (s6k > 0.f) ? sqrtf(sk2[b]) / sqrtf(s6k) : 0.f;
    sc[b * H_ + t] = rq * rk;
  }
}

// ---------------------------------------------------------------------------
// dwc_k: depthwise 3x3 conv on v -> dwcbuf[b][n][72] f16.
// ---------------------------------------------------------------------------
__global__ __launch_bounds__(256) void dwc_k(
    const f16* __restrict__ qkv, const float* __restrict__ dwc_w,
    const float* __restrict__ dwc_b, f16* __restrict__ out) {
  int b = blockIdx.y, n0 = blockIdx.x * 32, t = threadIdx.x;
  for (int idx = t; idx < 32 * HD_; idx += 256) {
    int nl = idx / HD_, e = idx % HD_;
    int n = n0 + nl, i = n >> 6, j = n & 63;
    float s = dwc_b[e];
#pragma unroll
    for (int di = 0; di < 3; di++) {
      int ii = i + di - 1;
      if (ii < 0 || ii >= S_) continue;
#pragma unroll
      for (int dj = 0; dj < 3; dj++) {
        int jj = j + dj - 1;
        if (jj < 0 || jj >= S_) continue;
        s += dwc_w[e * 9 + di * 3 + dj] *
             (float)qkv[(long)(b * N_ + ii * S_ + jj) * QKVC_ + C_ + HD_ + e];
      }
    }
    out[((long)b * N_ + n) * HD_ + e] = (f16)s;
  }
}

// ---------------------------------------------------------------------------
// attn_k: per (b,h,128-row block):  y = sc[b,h] * relu(q)^3 @ kvl + dwc,
// written in place over q (disjoint column slice per h).  MFMA 16x16x32 f16,
// K padded 72->96, N padded 72->80.  LDS: qs[128][104] (reused for y staging),
// kvs[80][104].  43.3 KB -> 3 blocks/CU.
// ---------------------------------------------------------------------------
#define AT_M 128
__global__ __launch_bounds__(256) void attn_k(
    f16* __restrict__ q,                 // read q, write y in place (qkv buf)
    const f16* __restrict__ kvT,         // [B][80][104]
    const float* __restrict__ sc,        // [B][H]
    const f16* __restrict__ dwcb) {      // [B][N][72]
  int nb = blockIdx.x, h = blockIdx.y, b = blockIdx.z;
  int n0 = nb * AT_M;
  int t = threadIdx.x;
  __shared__ f16 qs[AT_M][KT_K];     // 26,624 B  (relu^3 q, then y staging)
  __shared__ f16 kvs[KT_E][KT_K];    // 16,640 B

  // stage kvT (already padded/transposed) -- 1040 x 16B
  const f16* kvsrc = kvT + (long)b * KT_E * KT_K;
  for (int i = t; i < KT_E * KT_K / 8; i += 256)
    *(f16x8*)((f16*)kvs + (long)i * 8) = *(const f16x8*)(kvsrc + (long)i * 8);

  // stage q -> relu^3 (f16) ; 128 rows x 9 chunks of 8
  const f16* qbase = q + ((long)(b * N_ + n0)) * QKVC_ + h * HD_;
  for (int i = t; i < AT_M * 9; i += 256) {
    int r = i / 9, ch = i % 9;
    f16x8 v = *(const f16x8*)(qbase + (long)r * QKVC_ + ch * 8);
    f16x8 o;
#pragma unroll
    for (int u = 0; u < 8; u++) {
      float f = fmaxf((float)v[u], 0.f);
      o[u] = (f16)(f * f * f);
    }
    *(f16x8*)&qs[r][ch * 8] = o;
  }
  // zero K-pad cols 72..95 (cols 96..103 never read)
  f16x8 z = {(f16)0.f, (f16)0.f, (f16)0.f, (f16)0.f,
             (f16)0.f, (f16)0.f, (f16)0.f, (f16)0.f};
  for (int i = t; i < AT_M * 3; i += 256) {
    int r = i / 3, ch = i % 3;
    *(f16x8*)&qs[r][72 + ch * 8] = z;
  }
  __syncthreads();

  // MFMA: wave w owns rows w*32..w*32+31 (2 m-tiles), 5 n-tiles, 3 K-steps
  int w = t >> 6, lane = t & 63;
  int m16 = lane & 15, q4 = lane >> 4;
  f32x4 acc[2][5];
#pragma unroll
  for (int i = 0; i < 2; i++)
#pragma unroll
    for (int j = 0; j < 5; j++) acc[i][j] = (f32x4){0.f, 0.f, 0.f, 0.f};

#pragma unroll
  for (int k = 0; k < 96; k += 32) {
    f16x8 af[2], bf[5];
#pragma unroll
    for (int i = 0; i < 2; i++)
      af[i] = *(const f16x8*)&qs[w * 32 + i * 16 + m16][k + q4 * 8];
#pragma unroll
    for (int j = 0; j < 5; j++)
      bf[j] = *(const f16x8*)&kvs[j * 16 + m16][k + q4 * 8];
#pragma unroll
    for (int i = 0; i < 2; i++)
#pragma unroll
      for (int j = 0; j < 5; j++)
        acc[i][j] = __builtin_amdgcn_mfma_f32_16x16x32_f16(af[i], bf[j], acc[i][j], 0, 0, 0);
  }

  float s = sc[b * H_ + h];
  __syncthreads();   // all waves done reading qs -> reuse as y staging

  // D layout: col = lane&15, row = (lane>>4)*4 + r.  Mask cols >= 72 (j==4).
#pragma unroll
  for (int j = 0; j < 5; j++) {
    if (j == 4 && m16 >= 8) continue;
#pragma unroll
    for (int i = 0; i < 2; i++) {
#pragma unroll
      for (int r = 0; r < 4; r++)
        qs[w * 32 + i * 16 + q4 * 4 + r][j * 16 + m16] = (f16)(acc[i][j][r] * s);
    }
  }
  __syncthreads();

  // coalesced write: y = ys + dwc
  const f16* db = dwcb + ((long)(b * N_ + n0)) * HD_;
  f16* yb = q + ((long)(b * N_ + n0)) * QKVC_ + h * HD_;
  for (int i = t; i < AT_M * 9; i += 256) {
    int r = i / 9, ch = i % 9;
    f16x8 a = *(const f16x8*)&qs[r][ch * 8];
    f16x8 d = *(const f16x8*)(db + (long)r * HD_ + ch * 8);
    f16x8 o;
#pragma unroll
    for (int u = 0; u < 8; u++)
      o[u] = (f16)((float)a[u] + (float)d[u]);
    *(f16x8*)(yb + (long)r * QKVC_ + ch * 8) = o;
  }
}

// ---------------------------------------------------------------------------
extern "C" void kernel_launch(void* const* d_in, const int* in_sizes, int n_in,
                              void* d_out, int out_size, void* d_ws, size_t ws_size,
                              hipStream_t stream) {
  const float* x      = (const float*)d_in[0];
  const float* wq_w   = (const float*)d_in[1];
  const float* wq_b   = (const float*)d_in[2];
  const float* wkv_w  = (const float*)d_in[3];
  const float* wkv_b  = (const float*)d_in[4];
  const float* dwc_w  = (const float*)d_in[5];
  const float* dwc_b  = (const float*)d_in[6];
  const float* proj_w = (const float*)d_in[7];
  const float* proj_b = (const float*)d_in[8];
  float* out = (float*)d_out;
  char* ws = (char*)d_ws;

  // x_h (fp16 copy of x) lives in d_out's first half — dead before final GEMM.
  f16* x_h = (f16*)d_out;
  // Upper half of d_out: dwcbuf / kvT / sc — all consumed by attn_k,
  // which runs before the final GEMM overwrites d_out.
  char* dtop = (char*)d_out + (size_t)M_ * C_ * 2;        // +150,994,944
  f16* dwcb = (f16*)dtop;                                  // 9,437,184 B
  f16* kvT  = (f16*)(dtop + (size_t)B_ * N_ * HD_ * 2);    //   266,240 B
  float* sc = (float*)(dtop + (size_t)B_ * N_ * HD_ * 2
                            + (size_t)B_ * KT_E * KT_K * 2);

  size_t off = 0;
  f16* wqkv_t = (f16*)(ws + off); off += (size_t)QKVC_ * C_ * 2;  // 2,985,984
  f16* proj_t = (f16*)(ws + off); off += (size_t)C_ * C_ * 2;     // 2,654,208
  float* qkv_b = (float*)(ws + off); off += (size_t)QKVC_ * 4;    //     5,184
  off = (off + 255) & ~(size_t)255;
  f16* qkv   = (f16*)(ws + off); off += (size_t)M_ * QKVC_ * 2;   // 169,869,312
  char* zbase = ws + off;
  float* sq2  = (float*)(ws + off); off += 1024;
  float* sq6  = (float*)(ws + off); off += 1024;
  float* sk2  = (float*)(ws + off); off += 1024;
  float* sk6  = (float*)(ws + off); off += 1024;
  float* kvac = (float*)(ws + off); off += (size_t)B_ * HD_ * HD_ * 4;
  size_t zlen = (size_t)(ws + off - zbase);

  hipMemsetAsync(zbase, 0, zlen, stream);
  // fused bias [wq_b | wkv_b]
  hipMemcpyAsync(qkv_b, wq_b, (size_t)C_ * 4, hipMemcpyDeviceToDevice, stream);
  hipMemcpyAsync(qkv_b + C_, wkv_b, (size_t)KV_ * 4, hipMemcpyDeviceToDevice, stream);

  convx_k<<<dim3((M_ * C_) / (256 * 8)), 256, 0, stream>>>(x, x_h);
  // fused weight Wt[1296][1152]: rows 0..1151 = wq^T, rows 1152..1295 = wkv^T
  transc_k<<<dim3(C_ / 32, C_ / 32), 256, 0, stream>>>(wq_w, wqkv_t, C_, C_);
  transc_k<<<dim3(C_ / 32, (KV_ + 31) / 32), 256, 0, stream>>>(
      wkv_w, wqkv_t + (size_t)C_ * C_, C_, KV_);
  transc_k<<<dim3(C_ / 32, C_ / 32), 256, 0, stream>>>(proj_w, proj_t, C_, C_);

  // qkv = x @ [wq|wkv] + b   (M=65536, N=1296, K=1152) ; grid 512*11 = 5632
  gemm_bt<f16><<<dim3((M_ / BM) * 11), 256, 0, stream>>>(
      x_h, wqkv_t, qkv_b, qkv, M_, QKVC_, C_, C_, 11);

  qsums_k<<<dim3(32, B_), 384, 0, stream>>>(qkv, sq2, sq6);
  ksums_k<<<dim3(32, B_), 256, 0, stream>>>(qkv, sk2, sk6);
  kvacc_k<<<dim3(64, B_), 256, 0, stream>>>(qkv, kvac);

  prep_k<<<dim3(B_), 256, 0, stream>>>(kvac, sq2, sq6, sk2, sk6, kvT, sc);
  dwc_k<<<dim3(N_ / 32, B_), 256, 0, stream>>>(qkv, dwc_w, dwc_b, dwcb);

  attn_k<<<dim3(N_ / AT_M, H_, B_), 256, 0, stream>>>(qkv, kvT, sc, dwcb);

  // out = y @ proj + b  (A = q/y columns of qkv, lda=1296; fp32 store)
  gemm_bt<float><<<dim3((M_ / BM) * (C_ / BN)), 256, 0, stream>>>(
      qkv, proj_t, proj_b, out, M_, C_, C_, QKVC_, C_ / BN);
}